// Round 1
// baseline (8939.318 us; speedup 1.0000x reference)
//
#include <hip/hip_runtime.h>

// varletNetworks on MI355X — round 1: all-f32, algebraically restructured.
// Key identities: KN@grad(xn) = gather(KN@xn);  xe never materialized:
//   D = div(xe) maintained incrementally, S_acc = sum_l H*relu(A_l),
//   xe_out = (KNclose@KEopen)@xe_in + KNclose@S_acc^T.
// Layouts: node/edge-major [N,128] for all ws intermediates (coalesced 512B
// per node column, float4 per lane).

#define HSTEP 0.1f
#define TVEPS 1e-3f

__device__ inline float4 f4z() { return make_float4(0.f, 0.f, 0.f, 0.f); }

// ---------------------------------------------------------------------------
// E-style GEMM core: X in original [128,N] layout; block computes 64 columns
// x 128 outputs.  MODE 0: store transposed [N,128]. MODE 1: scatter +/- into
// Dacc (edge_div of the freshly computed columns).
// thread: ng = tid&15 (4 consecutive cols), og = tid>>4 (8 consecutive outs).
// ---------------------------------------------------------------------------
template <int MODE>
__global__ __launch_bounds__(256, 2) void gemm_e(
    const float* __restrict__ X, const float* __restrict__ Kmat, const int N,
    float* __restrict__ Yt, float* __restrict__ Dacc,
    const int* __restrict__ iInd, const int* __restrict__ jInd) {
  __shared__ float Xs[32 * 68];   // [kk][e] pad 68
  __shared__ float Ks[32 * 132];  // [kk][o] pad 132
  const int tid = threadIdx.x;
  const int ng = tid & 15, og = tid >> 4;
  const long e0 = (long)blockIdx.x * 64;

  float acc[4][8];
#pragma unroll
  for (int q = 0; q < 4; ++q)
#pragma unroll
    for (int j = 0; j < 8; ++j) acc[q][j] = 0.f;

  for (int kc = 0; kc < 128; kc += 32) {
    // stage X chunk: Xs[kk][e] = X[(kc+kk)*N + e0+e]
#pragma unroll
    for (int i = 0; i < 2; ++i) {
      int f4i = tid + 256 * i;  // 512 float4s
      int kk = f4i >> 4, e4 = (f4i & 15) << 2;
      long ge = e0 + e4;
      float4 v = f4z();
      if (ge + 3 < N) {
        v = *(const float4*)&X[(long)(kc + kk) * N + ge];
      } else {
        float* pv = &v.x;
        for (int q = 0; q < 4; ++q)
          if (ge + q < N) pv[q] = X[(long)(kc + kk) * N + ge + q];
      }
      *(float4*)&Xs[kk * 68 + e4] = v;
    }
    // stage K chunk transposed: Ks[kk][o] = Kmat[o*128 + kc + kk]
#pragma unroll
    for (int i = 0; i < 4; ++i) {
      int f4i = tid + 256 * i;  // 1024 float4s (128 o x 8)
      int o = f4i >> 3, c4 = (f4i & 7) << 2;
      float4 v = *(const float4*)&Kmat[o * 128 + kc + c4];
      Ks[(c4 + 0) * 132 + o] = v.x;
      Ks[(c4 + 1) * 132 + o] = v.y;
      Ks[(c4 + 2) * 132 + o] = v.z;
      Ks[(c4 + 3) * 132 + o] = v.w;
    }
    __syncthreads();
#pragma unroll
    for (int kk = 0; kk < 32; ++kk) {
      const float4 xq = *(const float4*)&Xs[kk * 68 + 4 * ng];
      const float4 k0 = *(const float4*)&Ks[kk * 132 + 8 * og];
      const float4 k1 = *(const float4*)&Ks[kk * 132 + 8 * og + 4];
      float xv[4] = {xq.x, xq.y, xq.z, xq.w};
      float kv[8] = {k0.x, k0.y, k0.z, k0.w, k1.x, k1.y, k1.z, k1.w};
#pragma unroll
      for (int q = 0; q < 4; ++q)
#pragma unroll
        for (int j = 0; j < 8; ++j) acc[q][j] = fmaf(xv[q], kv[j], acc[q][j]);
    }
    __syncthreads();
  }

  if (MODE == 0) {
#pragma unroll
    for (int q = 0; q < 4; ++q) {
      long e = e0 + 4 * ng + q;
      if (e < N) {
        *(float4*)&Yt[e * 128 + 8 * og] =
            make_float4(acc[q][0], acc[q][1], acc[q][2], acc[q][3]);
        *(float4*)&Yt[e * 128 + 8 * og + 4] =
            make_float4(acc[q][4], acc[q][5], acc[q][6], acc[q][7]);
      }
    }
  } else {
#pragma unroll
    for (int q = 0; q < 4; ++q) {
      long e = e0 + 4 * ng + q;
      if (e < N) {
        const int ii = iInd[e], jj = jInd[e];
        float* Di = Dacc + (long)ii * 128 + 8 * og;
        float* Dj = Dacc + (long)jj * 128 + 8 * og;
#pragma unroll
        for (int j = 0; j < 8; ++j) {
          atomicAdd(Di + j, acc[q][j]);
          atomicAdd(Dj + j, -acc[q][j]);
        }
      }
    }
  }
}

// ---------------------------------------------------------------------------
// N-style GEMM core: X in [N,128] layout; out[n][o] = sum_k X[n][k]*Kmat[o][k]
// MODE 0: store [N,128].  MODE 1: relu + store + per-o sum/sumsq stats.
// MODE 2: store transposed into a [128,N] output (close_node).
// ---------------------------------------------------------------------------
template <int MODE>
__global__ __launch_bounds__(256, 2) void gemm_n(
    const float* __restrict__ X, const float* __restrict__ Kmat, const int N,
    float* __restrict__ Y, float* __restrict__ statS,
    float* __restrict__ statQ) {
  __shared__ float Xs[64 * 33];   // [n][kk] pad 33
  __shared__ float Ks[32 * 132];  // [kk][o]
  __shared__ float red[(MODE == 1) ? 2 * 128 * 17 : 4];
  const int tid = threadIdx.x;
  const int ng = tid & 15, og = tid >> 4;
  const long n0 = (long)blockIdx.x * 64;

  float acc[4][8];
#pragma unroll
  for (int q = 0; q < 4; ++q)
#pragma unroll
    for (int j = 0; j < 8; ++j) acc[q][j] = 0.f;

  for (int kc = 0; kc < 128; kc += 32) {
#pragma unroll
    for (int i = 0; i < 2; ++i) {
      int f4i = tid + 256 * i;  // 512 float4s
      int n = f4i >> 3, c4 = (f4i & 7) << 2;
      long gn = n0 + n;
      float4 v = f4z();
      if (gn < N) v = *(const float4*)&X[gn * 128 + kc + c4];
      Xs[n * 33 + c4 + 0] = v.x;
      Xs[n * 33 + c4 + 1] = v.y;
      Xs[n * 33 + c4 + 2] = v.z;
      Xs[n * 33 + c4 + 3] = v.w;
    }
#pragma unroll
    for (int i = 0; i < 4; ++i) {
      int f4i = tid + 256 * i;
      int o = f4i >> 3, c4 = (f4i & 7) << 2;
      float4 v = *(const float4*)&Kmat[o * 128 + kc + c4];
      Ks[(c4 + 0) * 132 + o] = v.x;
      Ks[(c4 + 1) * 132 + o] = v.y;
      Ks[(c4 + 2) * 132 + o] = v.z;
      Ks[(c4 + 3) * 132 + o] = v.w;
    }
    __syncthreads();
#pragma unroll
    for (int kk = 0; kk < 32; ++kk) {
      float xv[4];
#pragma unroll
      for (int q = 0; q < 4; ++q) xv[q] = Xs[(4 * ng + q) * 33 + kk];
      const float4 k0 = *(const float4*)&Ks[kk * 132 + 8 * og];
      const float4 k1 = *(const float4*)&Ks[kk * 132 + 8 * og + 4];
      float kv[8] = {k0.x, k0.y, k0.z, k0.w, k1.x, k1.y, k1.z, k1.w};
#pragma unroll
      for (int q = 0; q < 4; ++q)
#pragma unroll
        for (int j = 0; j < 8; ++j) acc[q][j] = fmaf(xv[q], kv[j], acc[q][j]);
    }
    __syncthreads();
  }

  if (MODE == 0) {
#pragma unroll
    for (int q = 0; q < 4; ++q) {
      long n = n0 + 4 * ng + q;
      if (n < N) {
        *(float4*)&Y[n * 128 + 8 * og] =
            make_float4(acc[q][0], acc[q][1], acc[q][2], acc[q][3]);
        *(float4*)&Y[n * 128 + 8 * og + 4] =
            make_float4(acc[q][4], acc[q][5], acc[q][6], acc[q][7]);
      }
    }
  } else if (MODE == 1) {
#pragma unroll
    for (int q = 0; q < 4; ++q)
#pragma unroll
      for (int j = 0; j < 8; ++j) acc[q][j] = fmaxf(acc[q][j], 0.f);
#pragma unroll
    for (int q = 0; q < 4; ++q) {
      long n = n0 + 4 * ng + q;
      if (n < N) {
        *(float4*)&Y[n * 128 + 8 * og] =
            make_float4(acc[q][0], acc[q][1], acc[q][2], acc[q][3]);
        *(float4*)&Y[n * 128 + 8 * og + 4] =
            make_float4(acc[q][4], acc[q][5], acc[q][6], acc[q][7]);
      }
    }
    // stats: rows n>=N contributed exact zeros (staged zeros -> relu 0)
    float* redS = red;
    float* redQ = red + 128 * 17;
#pragma unroll
    for (int j = 0; j < 8; ++j) {
      int o = 8 * og + j;
      float s = acc[0][j] + acc[1][j] + acc[2][j] + acc[3][j];
      float qq = acc[0][j] * acc[0][j] + acc[1][j] * acc[1][j] +
                 acc[2][j] * acc[2][j] + acc[3][j] * acc[3][j];
      redS[o * 17 + ng] = s;
      redQ[o * 17 + ng] = qq;
    }
    __syncthreads();
    if (tid < 128) {
      float s = 0.f, qq = 0.f;
#pragma unroll
      for (int g = 0; g < 16; ++g) {
        s += redS[tid * 17 + g];
        qq += redQ[tid * 17 + g];
      }
      atomicAdd(&statS[tid], s);
      atomicAdd(&statQ[tid], qq);
    }
  } else {  // MODE 2: transposed store
    long n = n0 + 4 * ng;
#pragma unroll
    for (int j = 0; j < 8; ++j) {
      long o = 8 * og + j;
      float4 v = make_float4(acc[0][j], acc[1][j], acc[2][j], acc[3][j]);
      if (n + 3 < N) {
        *(float4*)&Y[o * N + n] = v;
      } else {
        const float* pv = &v.x;
        for (int q = 0; q < 4; ++q)
          if (n + q < N) Y[o * N + n + q] = pv[q];
      }
    }
  }
}

// ---------------------------------------------------------------------------
// close_edge: out[o][e] = sum_k M1[o][k]*Xe[k][e] + sum_k Kc[o][k]*Sacc[e][k]
// ---------------------------------------------------------------------------
__global__ __launch_bounds__(256, 2) void close_edge(
    const float* __restrict__ Xe, const float* __restrict__ Sacc,
    const float* __restrict__ M1, const float* __restrict__ Kc, const int N,
    float* __restrict__ out) {
  __shared__ float Xs1[32 * 68];
  __shared__ float Xs2[64 * 33];
  __shared__ float Ks1[32 * 132];
  __shared__ float Ks2[32 * 132];
  const int tid = threadIdx.x;
  const int ng = tid & 15, og = tid >> 4;
  const long e0 = (long)blockIdx.x * 64;

  float acc[4][8];
#pragma unroll
  for (int q = 0; q < 4; ++q)
#pragma unroll
    for (int j = 0; j < 8; ++j) acc[q][j] = 0.f;

  for (int kc = 0; kc < 128; kc += 32) {
#pragma unroll
    for (int i = 0; i < 2; ++i) {
      int f4i = tid + 256 * i;
      int kk = f4i >> 4, e4 = (f4i & 15) << 2;
      long ge = e0 + e4;
      float4 v = f4z();
      if (ge + 3 < N) {
        v = *(const float4*)&Xe[(long)(kc + kk) * N + ge];
      } else {
        float* pv = &v.x;
        for (int q = 0; q < 4; ++q)
          if (ge + q < N) pv[q] = Xe[(long)(kc + kk) * N + ge + q];
      }
      *(float4*)&Xs1[kk * 68 + e4] = v;
    }
#pragma unroll
    for (int i = 0; i < 2; ++i) {
      int f4i = tid + 256 * i;
      int n = f4i >> 3, c4 = (f4i & 7) << 2;
      long ge = e0 + n;
      float4 v = f4z();
      if (ge < N) v = *(const float4*)&Sacc[ge * 128 + kc + c4];
      Xs2[n * 33 + c4 + 0] = v.x;
      Xs2[n * 33 + c4 + 1] = v.y;
      Xs2[n * 33 + c4 + 2] = v.z;
      Xs2[n * 33 + c4 + 3] = v.w;
    }
#pragma unroll
    for (int i = 0; i < 4; ++i) {
      int f4i = tid + 256 * i;
      int o = f4i >> 3, c4 = (f4i & 7) << 2;
      float4 a = *(const float4*)&M1[o * 128 + kc + c4];
      float4 b = *(const float4*)&Kc[o * 128 + kc + c4];
      Ks1[(c4 + 0) * 132 + o] = a.x;
      Ks1[(c4 + 1) * 132 + o] = a.y;
      Ks1[(c4 + 2) * 132 + o] = a.z;
      Ks1[(c4 + 3) * 132 + o] = a.w;
      Ks2[(c4 + 0) * 132 + o] = b.x;
      Ks2[(c4 + 1) * 132 + o] = b.y;
      Ks2[(c4 + 2) * 132 + o] = b.z;
      Ks2[(c4 + 3) * 132 + o] = b.w;
    }
    __syncthreads();
#pragma unroll
    for (int kk = 0; kk < 32; ++kk) {
      const float4 xq = *(const float4*)&Xs1[kk * 68 + 4 * ng];
      float x1[4] = {xq.x, xq.y, xq.z, xq.w};
      float x2[4];
#pragma unroll
      for (int q = 0; q < 4; ++q) x2[q] = Xs2[(4 * ng + q) * 33 + kk];
      const float4 a0 = *(const float4*)&Ks1[kk * 132 + 8 * og];
      const float4 a1 = *(const float4*)&Ks1[kk * 132 + 8 * og + 4];
      const float4 b0 = *(const float4*)&Ks2[kk * 132 + 8 * og];
      const float4 b1 = *(const float4*)&Ks2[kk * 132 + 8 * og + 4];
      float k1[8] = {a0.x, a0.y, a0.z, a0.w, a1.x, a1.y, a1.z, a1.w};
      float k2[8] = {b0.x, b0.y, b0.z, b0.w, b1.x, b1.y, b1.z, b1.w};
#pragma unroll
      for (int q = 0; q < 4; ++q)
#pragma unroll
        for (int j = 0; j < 8; ++j) {
          acc[q][j] = fmaf(x1[q], k1[j], acc[q][j]);
          acc[q][j] = fmaf(x2[q], k2[j], acc[q][j]);
        }
    }
    __syncthreads();
  }

  long e = e0 + 4 * ng;
#pragma unroll
  for (int j = 0; j < 8; ++j) {
    long o = 8 * og + j;
    float4 v = make_float4(acc[0][j], acc[1][j], acc[2][j], acc[3][j]);
    if (e + 3 < N) {
      *(float4*)&out[o * N + e] = v;
    } else {
      const float* pv = &v.x;
      for (int q = 0; q < 4; ++q)
        if (e + q < N) out[o * N + e + q] = pv[q];
    }
  }
}

// ---------------------------------------------------------------------------
// Edge pass 1: accumulate per-channel sum / sumsq of y = W[i]-W[j].
// lanes 0..31 = one edge's 128 channels (float4/lane), 8 edge-slots/block-row.
// ---------------------------------------------------------------------------
__global__ __launch_bounds__(256) void edge_pass1(
    const float* __restrict__ W, const int* __restrict__ iInd,
    const int* __restrict__ jInd, const int nE, float* __restrict__ statS,
    float* __restrict__ statQ) {
  __shared__ float4 rs[256];
  __shared__ float4 rq[256];
  const int tid = threadIdx.x;
  const int cg = tid & 31, slot = tid >> 5;
  const float4* W4 = (const float4*)W;
  float4 s = f4z(), q = f4z();
  long start = (long)blockIdx.x * 512;
  long end = start + 512;
  if (end > nE) end = nE;
  for (long e = start + slot; e < end; e += 8) {
    const int ii = iInd[e], jj = jInd[e];
    const float4 wi = W4[(long)ii * 32 + cg];
    const float4 wj = W4[(long)jj * 32 + cg];
    const float y0 = wi.x - wj.x, y1 = wi.y - wj.y;
    const float y2 = wi.z - wj.z, y3 = wi.w - wj.w;
    s.x += y0; s.y += y1; s.z += y2; s.w += y3;
    q.x = fmaf(y0, y0, q.x); q.y = fmaf(y1, y1, q.y);
    q.z = fmaf(y2, y2, q.z); q.w = fmaf(y3, y3, q.w);
  }
  rs[tid] = s;
  rq[tid] = q;
  __syncthreads();
  if (tid < 32) {
    float4 S = rs[tid], Q = rq[tid];
#pragma unroll
    for (int g = 1; g < 8; ++g) {
      float4 a = rs[tid + 32 * g], b = rq[tid + 32 * g];
      S.x += a.x; S.y += a.y; S.z += a.z; S.w += a.w;
      Q.x += b.x; Q.y += b.y; Q.z += b.z; Q.w += b.w;
    }
    atomicAdd(&statS[tid * 4 + 0], S.x);
    atomicAdd(&statS[tid * 4 + 1], S.y);
    atomicAdd(&statS[tid * 4 + 2], S.z);
    atomicAdd(&statS[tid * 4 + 3], S.w);
    atomicAdd(&statQ[tid * 4 + 0], Q.x);
    atomicAdd(&statQ[tid * 4 + 1], Q.y);
    atomicAdd(&statQ[tid * 4 + 2], Q.z);
    atomicAdd(&statQ[tid * 4 + 3], Q.w);
  }
}

// ---------------------------------------------------------------------------
// Edge pass 2: r = H*relu((y-mean)*rsig); Sacc (=) or (+=) r; D += div(r).
// ---------------------------------------------------------------------------
template <bool FIRST>
__global__ __launch_bounds__(256) void edge_pass2(
    const float* __restrict__ W, const int* __restrict__ iInd,
    const int* __restrict__ jInd, const int nE, const float* __restrict__ mean,
    const float* __restrict__ rsig, float* __restrict__ Sacc,
    float* __restrict__ Dacc) {
  const int tid = threadIdx.x;
  const int cg = tid & 31, slot = tid >> 5;
  const float4 mu = *(const float4*)&mean[cg * 4];
  const float4 sg = *(const float4*)&rsig[cg * 4];
  const float4* W4 = (const float4*)W;
  float4* S4 = (float4*)Sacc;
  long start = (long)blockIdx.x * 512;
  long end = start + 512;
  if (end > nE) end = nE;
  for (long e = start + slot; e < end; e += 8) {
    const int ii = iInd[e], jj = jInd[e];
    const float4 wi = W4[(long)ii * 32 + cg];
    const float4 wj = W4[(long)jj * 32 + cg];
    const float r0 = fmaxf(((wi.x - wj.x) - mu.x) * sg.x, 0.f) * HSTEP;
    const float r1 = fmaxf(((wi.y - wj.y) - mu.y) * sg.y, 0.f) * HSTEP;
    const float r2 = fmaxf(((wi.z - wj.z) - mu.z) * sg.z, 0.f) * HSTEP;
    const float r3 = fmaxf(((wi.w - wj.w) - mu.w) * sg.w, 0.f) * HSTEP;
    float4 sv;
    if (FIRST) {
      sv = make_float4(r0, r1, r2, r3);
    } else {
      sv = S4[e * 32 + cg];
      sv.x += r0; sv.y += r1; sv.z += r2; sv.w += r3;
    }
    S4[e * 32 + cg] = sv;
    float* Di = Dacc + (long)ii * 128 + cg * 4;
    float* Dj = Dacc + (long)jj * 128 + cg * 4;
    if (r0 > 0.f) { atomicAdd(Di + 0, r0); atomicAdd(Dj + 0, -r0); }
    if (r1 > 0.f) { atomicAdd(Di + 1, r1); atomicAdd(Dj + 1, -r1); }
    if (r2 > 0.f) { atomicAdd(Di + 2, r2); atomicAdd(Dj + 2, -r2); }
    if (r3 > 0.f) { atomicAdd(Di + 3, r3); atomicAdd(Dj + 3, -r3); }
  }
}

// ---------------------------------------------------------------------------
__global__ void fin_stats(const float* __restrict__ S,
                          const float* __restrict__ Q, const float cnt,
                          float* __restrict__ mean, float* __restrict__ rsig) {
  const int c = threadIdx.x;  // 128
  const float mu = S[c] / cnt;
  const float var = Q[c] - cnt * mu * mu;
  mean[c] = mu;
  rsig[c] = rsqrtf(var + TVEPS);
}

__global__ __launch_bounds__(256) void apply_node(
    const float* __restrict__ R, const float* __restrict__ mean,
    const float* __restrict__ rsig, float* __restrict__ xnt,
    const long total4) {
  const long idx = (long)blockIdx.x * 256 + threadIdx.x;
  if (idx >= total4) return;
  const int o4 = (int)(idx & 31) * 4;
  const float4 m = *(const float4*)&mean[o4];
  const float4 s = *(const float4*)&rsig[o4];
  const float4 r = ((const float4*)R)[idx];
  float4 x = ((float4*)xnt)[idx];
  x.x += HSTEP * fmaxf((r.x - m.x) * s.x, 0.f);
  x.y += HSTEP * fmaxf((r.y - m.y) * s.y, 0.f);
  x.z += HSTEP * fmaxf((r.z - m.z) * s.z, 0.f);
  x.w += HSTEP * fmaxf((r.w - m.w) * s.w, 0.f);
  ((float4*)xnt)[idx] = x;
}

__global__ void make_m1(const float* __restrict__ KNclose,
                        const float* __restrict__ KEopen,
                        float* __restrict__ M1) {
  const int idx = blockIdx.x * 256 + threadIdx.x;  // 16384
  const int o = idx >> 7, k = idx & 127;
  float s = 0.f;
  for (int m = 0; m < 128; ++m)
    s = fmaf(KNclose[o * 128 + m], KEopen[m * 128 + k], s);
  M1[idx] = s;
}

// ---------------------------------------------------------------------------
extern "C" void kernel_launch(void* const* d_in, const int* in_sizes, int n_in,
                              void* d_out, int out_size, void* d_ws,
                              size_t ws_size, hipStream_t stream) {
  const float* xn = (const float*)d_in[0];
  const float* xe = (const float*)d_in[1];
  const int* iInd = (const int*)d_in[2];
  const int* jInd = (const int*)d_in[3];
  const float* KNopen = (const float*)d_in[4];
  const float* KEopen = (const float*)d_in[5];
  const float* KNclose = (const float*)d_in[6];
  // d_in[7] = KEclose — unused by the reference (it uses KNclose for xe too)
  const float* KN = (const float*)d_in[8];
  const float* KE = (const float*)d_in[9];

  const int nN = in_sizes[0] / 128;
  const int nE = in_sizes[2];

  float* out_xn = (float*)d_out;
  float* out_xe = (float*)d_out + (size_t)128 * nN;

  float* ws = (float*)d_ws;
  size_t off = 0;
  float* Sacc = ws + off; off += (size_t)nE * 128;   // 256 MB
  float* W    = ws + off; off += (size_t)nN * 128;   // also reused as R
  float* Dacc = ws + off; off += (size_t)nN * 128;
  float* xnt  = ws + off; off += (size_t)nN * 128;
  float* M1   = ws + off; off += 16384;
  float* stats = ws + off;  // 1024 floats
  float* statS = stats;        float* statQ = stats + 128;
  float* meanE = stats + 256;  float* rsigE = stats + 384;
  float* statS2 = stats + 512; float* statQ2 = stats + 640;
  float* meanN = stats + 768;  float* rsigN = stats + 896;
  float* R = W;  // alias: W dead after pass2, R produced after

  const int gN = (nN + 63) / 64;
  const int gE = (nE + 63) / 64;
  const int gP = (nE + 511) / 512;
  const int gA = (int)(((long)nN * 32 + 255) / 256);

  hipMemsetAsync(Dacc, 0, (size_t)nN * 128 * sizeof(float), stream);

  // open: xnt = (KNopen@xn)^T ; D = div(KEopen@xe) (xe_open never stored)
  gemm_e<0><<<gN, 256, 0, stream>>>(xn, KNopen, nN, xnt, nullptr, nullptr,
                                    nullptr);
  gemm_e<1><<<gE, 256, 0, stream>>>(xe, KEopen, nE, nullptr, Dacc, iInd, jInd);
  make_m1<<<64, 256, 0, stream>>>(KNclose, KEopen, M1);

  for (int layer = 0; layer < 4; ++layer) {
    hipMemsetAsync(stats, 0, 1024 * sizeof(float), stream);
    // W = (KN_l @ xn)^T
    gemm_n<0><<<gN, 256, 0, stream>>>(xnt, KN + layer * 16384, nN, W, nullptr,
                                      nullptr);
    edge_pass1<<<gP, 256, 0, stream>>>(W, iInd, jInd, nE, statS, statQ);
    fin_stats<<<1, 128, 0, stream>>>(statS, statQ, (float)nE, meanE, rsigE);
    if (layer == 0)
      edge_pass2<true><<<gP, 256, 0, stream>>>(W, iInd, jInd, nE, meanE, rsigE,
                                               Sacc, Dacc);
    else
      edge_pass2<false><<<gP, 256, 0, stream>>>(W, iInd, jInd, nE, meanE,
                                                rsigE, Sacc, Dacc);
    // R = relu(KE_l @ D) with stats
    gemm_n<1><<<gN, 256, 0, stream>>>(Dacc, KE + layer * 16384, nN, R, statS2,
                                      statQ2);
    fin_stats<<<1, 128, 0, stream>>>(statS2, statQ2, (float)nN, meanN, rsigN);
    apply_node<<<gA, 256, 0, stream>>>(R, meanN, rsigN, xnt, (long)nN * 32);
  }

  // close
  gemm_n<2><<<gN, 256, 0, stream>>>(xnt, KNclose, nN, out_xn, nullptr,
                                    nullptr);
  close_edge<<<gE, 256, 0, stream>>>(xe, Sacc, M1, KNclose, nE, out_xe);
}

// Round 2
// 3526.996 us; speedup vs baseline: 2.5345x; 2.5345x over previous
//
#include <hip/hip_runtime.h>

// varletNetworks on MI355X — round 2: scatter->gather via on-device CSR.
// Round-1 counters: gemm_e<1> 3.4ms at VALUBusy 5.4%, WRITE_SIZE 4GB ==
// f32 atomicAdd write-through (~31B/atomic). Fix: no float atomics anywhere.
//   Eopen = (KEopen@xe)^T stored [nE,128]; D0[n] = sum_adj(n) +-Eopen[e,:]
//   per layer: Sacc updated coalesced; Dacc = D0 + csr_gather(Sacc).
// Sacc aliases Eopen (Eopen dead after div_gather<OPEN>).

#define HSTEP 0.1f
#define TVEPS 1e-3f

__device__ inline float4 f4z() { return make_float4(0.f, 0.f, 0.f, 0.f); }

// ---------------------------------------------------------------------------
// E-style GEMM: X in [128,N] layout; block = 64 cols x 128 outs; store [N,128]
// ---------------------------------------------------------------------------
__global__ __launch_bounds__(256, 2) void gemm_e(
    const float* __restrict__ X, const float* __restrict__ Kmat, const int N,
    float* __restrict__ Yt) {
  __shared__ float Xs[32 * 68];   // [kk][e] pad 68
  __shared__ float Ks[32 * 132];  // [kk][o] pad 132
  const int tid = threadIdx.x;
  const int ng = tid & 15, og = tid >> 4;
  const long e0 = (long)blockIdx.x * 64;

  float acc[4][8];
#pragma unroll
  for (int q = 0; q < 4; ++q)
#pragma unroll
    for (int j = 0; j < 8; ++j) acc[q][j] = 0.f;

  for (int kc = 0; kc < 128; kc += 32) {
#pragma unroll
    for (int i = 0; i < 2; ++i) {
      int f4i = tid + 256 * i;  // 512 float4s
      int kk = f4i >> 4, e4 = (f4i & 15) << 2;
      long ge = e0 + e4;
      float4 v = f4z();
      if (ge + 3 < N) {
        v = *(const float4*)&X[(long)(kc + kk) * N + ge];
      } else {
        float* pv = &v.x;
        for (int q = 0; q < 4; ++q)
          if (ge + q < N) pv[q] = X[(long)(kc + kk) * N + ge + q];
      }
      *(float4*)&Xs[kk * 68 + e4] = v;
    }
#pragma unroll
    for (int i = 0; i < 4; ++i) {
      int f4i = tid + 256 * i;  // 1024 float4s
      int o = f4i >> 3, c4 = (f4i & 7) << 2;
      float4 v = *(const float4*)&Kmat[o * 128 + kc + c4];
      Ks[(c4 + 0) * 132 + o] = v.x;
      Ks[(c4 + 1) * 132 + o] = v.y;
      Ks[(c4 + 2) * 132 + o] = v.z;
      Ks[(c4 + 3) * 132 + o] = v.w;
    }
    __syncthreads();
#pragma unroll
    for (int kk = 0; kk < 32; ++kk) {
      const float4 xq = *(const float4*)&Xs[kk * 68 + 4 * ng];
      const float4 k0 = *(const float4*)&Ks[kk * 132 + 8 * og];
      const float4 k1 = *(const float4*)&Ks[kk * 132 + 8 * og + 4];
      float xv[4] = {xq.x, xq.y, xq.z, xq.w};
      float kv[8] = {k0.x, k0.y, k0.z, k0.w, k1.x, k1.y, k1.z, k1.w};
#pragma unroll
      for (int q = 0; q < 4; ++q)
#pragma unroll
        for (int j = 0; j < 8; ++j) acc[q][j] = fmaf(xv[q], kv[j], acc[q][j]);
    }
    __syncthreads();
  }

#pragma unroll
  for (int q = 0; q < 4; ++q) {
    long e = e0 + 4 * ng + q;
    if (e < N) {
      *(float4*)&Yt[e * 128 + 8 * og] =
          make_float4(acc[q][0], acc[q][1], acc[q][2], acc[q][3]);
      *(float4*)&Yt[e * 128 + 8 * og + 4] =
          make_float4(acc[q][4], acc[q][5], acc[q][6], acc[q][7]);
    }
  }
}

// ---------------------------------------------------------------------------
// N-style GEMM: X in [N,128]; out[n][o] = sum_k X[n][k]*Kmat[o][k]
// MODE 0: store [N,128]. MODE 1: relu+store+stats. MODE 2: store [128,N].
// ---------------------------------------------------------------------------
template <int MODE>
__global__ __launch_bounds__(256, 2) void gemm_n(
    const float* __restrict__ X, const float* __restrict__ Kmat, const int N,
    float* __restrict__ Y, float* __restrict__ statS,
    float* __restrict__ statQ) {
  __shared__ float Xs[64 * 33];
  __shared__ float Ks[32 * 132];
  __shared__ float red[(MODE == 1) ? 2 * 128 * 17 : 4];
  const int tid = threadIdx.x;
  const int ng = tid & 15, og = tid >> 4;
  const long n0 = (long)blockIdx.x * 64;

  float acc[4][8];
#pragma unroll
  for (int q = 0; q < 4; ++q)
#pragma unroll
    for (int j = 0; j < 8; ++j) acc[q][j] = 0.f;

  for (int kc = 0; kc < 128; kc += 32) {
#pragma unroll
    for (int i = 0; i < 2; ++i) {
      int f4i = tid + 256 * i;
      int n = f4i >> 3, c4 = (f4i & 7) << 2;
      long gn = n0 + n;
      float4 v = f4z();
      if (gn < N) v = *(const float4*)&X[gn * 128 + kc + c4];
      Xs[n * 33 + c4 + 0] = v.x;
      Xs[n * 33 + c4 + 1] = v.y;
      Xs[n * 33 + c4 + 2] = v.z;
      Xs[n * 33 + c4 + 3] = v.w;
    }
#pragma unroll
    for (int i = 0; i < 4; ++i) {
      int f4i = tid + 256 * i;
      int o = f4i >> 3, c4 = (f4i & 7) << 2;
      float4 v = *(const float4*)&Kmat[o * 128 + kc + c4];
      Ks[(c4 + 0) * 132 + o] = v.x;
      Ks[(c4 + 1) * 132 + o] = v.y;
      Ks[(c4 + 2) * 132 + o] = v.z;
      Ks[(c4 + 3) * 132 + o] = v.w;
    }
    __syncthreads();
#pragma unroll
    for (int kk = 0; kk < 32; ++kk) {
      float xv[4];
#pragma unroll
      for (int q = 0; q < 4; ++q) xv[q] = Xs[(4 * ng + q) * 33 + kk];
      const float4 k0 = *(const float4*)&Ks[kk * 132 + 8 * og];
      const float4 k1 = *(const float4*)&Ks[kk * 132 + 8 * og + 4];
      float kv[8] = {k0.x, k0.y, k0.z, k0.w, k1.x, k1.y, k1.z, k1.w};
#pragma unroll
      for (int q = 0; q < 4; ++q)
#pragma unroll
        for (int j = 0; j < 8; ++j) acc[q][j] = fmaf(xv[q], kv[j], acc[q][j]);
    }
    __syncthreads();
  }

  if (MODE == 0) {
#pragma unroll
    for (int q = 0; q < 4; ++q) {
      long n = n0 + 4 * ng + q;
      if (n < N) {
        *(float4*)&Y[n * 128 + 8 * og] =
            make_float4(acc[q][0], acc[q][1], acc[q][2], acc[q][3]);
        *(float4*)&Y[n * 128 + 8 * og + 4] =
            make_float4(acc[q][4], acc[q][5], acc[q][6], acc[q][7]);
      }
    }
  } else if (MODE == 1) {
#pragma unroll
    for (int q = 0; q < 4; ++q)
#pragma unroll
      for (int j = 0; j < 8; ++j) acc[q][j] = fmaxf(acc[q][j], 0.f);
#pragma unroll
    for (int q = 0; q < 4; ++q) {
      long n = n0 + 4 * ng + q;
      if (n < N) {
        *(float4*)&Y[n * 128 + 8 * og] =
            make_float4(acc[q][0], acc[q][1], acc[q][2], acc[q][3]);
        *(float4*)&Y[n * 128 + 8 * og + 4] =
            make_float4(acc[q][4], acc[q][5], acc[q][6], acc[q][7]);
      }
    }
    float* redS = red;
    float* redQ = red + 128 * 17;
#pragma unroll
    for (int j = 0; j < 8; ++j) {
      int o = 8 * og + j;
      float s = acc[0][j] + acc[1][j] + acc[2][j] + acc[3][j];
      float qq = acc[0][j] * acc[0][j] + acc[1][j] * acc[1][j] +
                 acc[2][j] * acc[2][j] + acc[3][j] * acc[3][j];
      redS[o * 17 + ng] = s;
      redQ[o * 17 + ng] = qq;
    }
    __syncthreads();
    if (tid < 128) {
      float s = 0.f, qq = 0.f;
#pragma unroll
      for (int g = 0; g < 16; ++g) {
        s += redS[tid * 17 + g];
        qq += redQ[tid * 17 + g];
      }
      atomicAdd(&statS[tid], s);
      atomicAdd(&statQ[tid], qq);
    }
  } else {  // MODE 2: transposed store
    long n = n0 + 4 * ng;
#pragma unroll
    for (int j = 0; j < 8; ++j) {
      long o = 8 * og + j;
      float4 v = make_float4(acc[0][j], acc[1][j], acc[2][j], acc[3][j]);
      if (n + 3 < N) {
        *(float4*)&Y[o * N + n] = v;
      } else {
        const float* pv = &v.x;
        for (int q = 0; q < 4; ++q)
          if (n + q < N) Y[o * N + n + q] = pv[q];
      }
    }
  }
}

// ---------------------------------------------------------------------------
// close_edge: out[o][e] = sum_k M1[o][k]*Xe[k][e] + sum_k Kc[o][k]*Sacc[e][k]
// ---------------------------------------------------------------------------
__global__ __launch_bounds__(256, 2) void close_edge(
    const float* __restrict__ Xe, const float* __restrict__ Sacc,
    const float* __restrict__ M1, const float* __restrict__ Kc, const int N,
    float* __restrict__ out) {
  __shared__ float Xs1[32 * 68];
  __shared__ float Xs2[64 * 33];
  __shared__ float Ks1[32 * 132];
  __shared__ float Ks2[32 * 132];
  const int tid = threadIdx.x;
  const int ng = tid & 15, og = tid >> 4;
  const long e0 = (long)blockIdx.x * 64;

  float acc[4][8];
#pragma unroll
  for (int q = 0; q < 4; ++q)
#pragma unroll
    for (int j = 0; j < 8; ++j) acc[q][j] = 0.f;

  for (int kc = 0; kc < 128; kc += 32) {
#pragma unroll
    for (int i = 0; i < 2; ++i) {
      int f4i = tid + 256 * i;
      int kk = f4i >> 4, e4 = (f4i & 15) << 2;
      long ge = e0 + e4;
      float4 v = f4z();
      if (ge + 3 < N) {
        v = *(const float4*)&Xe[(long)(kc + kk) * N + ge];
      } else {
        float* pv = &v.x;
        for (int q = 0; q < 4; ++q)
          if (ge + q < N) pv[q] = Xe[(long)(kc + kk) * N + ge + q];
      }
      *(float4*)&Xs1[kk * 68 + e4] = v;
    }
#pragma unroll
    for (int i = 0; i < 2; ++i) {
      int f4i = tid + 256 * i;
      int n = f4i >> 3, c4 = (f4i & 7) << 2;
      long ge = e0 + n;
      float4 v = f4z();
      if (ge < N) v = *(const float4*)&Sacc[ge * 128 + kc + c4];
      Xs2[n * 33 + c4 + 0] = v.x;
      Xs2[n * 33 + c4 + 1] = v.y;
      Xs2[n * 33 + c4 + 2] = v.z;
      Xs2[n * 33 + c4 + 3] = v.w;
    }
#pragma unroll
    for (int i = 0; i < 4; ++i) {
      int f4i = tid + 256 * i;
      int o = f4i >> 3, c4 = (f4i & 7) << 2;
      float4 a = *(const float4*)&M1[o * 128 + kc + c4];
      float4 b = *(const float4*)&Kc[o * 128 + kc + c4];
      Ks1[(c4 + 0) * 132 + o] = a.x;
      Ks1[(c4 + 1) * 132 + o] = a.y;
      Ks1[(c4 + 2) * 132 + o] = a.z;
      Ks1[(c4 + 3) * 132 + o] = a.w;
      Ks2[(c4 + 0) * 132 + o] = b.x;
      Ks2[(c4 + 1) * 132 + o] = b.y;
      Ks2[(c4 + 2) * 132 + o] = b.z;
      Ks2[(c4 + 3) * 132 + o] = b.w;
    }
    __syncthreads();
#pragma unroll
    for (int kk = 0; kk < 32; ++kk) {
      const float4 xq = *(const float4*)&Xs1[kk * 68 + 4 * ng];
      float x1[4] = {xq.x, xq.y, xq.z, xq.w};
      float x2[4];
#pragma unroll
      for (int q = 0; q < 4; ++q) x2[q] = Xs2[(4 * ng + q) * 33 + kk];
      const float4 a0 = *(const float4*)&Ks1[kk * 132 + 8 * og];
      const float4 a1 = *(const float4*)&Ks1[kk * 132 + 8 * og + 4];
      const float4 b0 = *(const float4*)&Ks2[kk * 132 + 8 * og];
      const float4 b1 = *(const float4*)&Ks2[kk * 132 + 8 * og + 4];
      float k1[8] = {a0.x, a0.y, a0.z, a0.w, a1.x, a1.y, a1.z, a1.w};
      float k2[8] = {b0.x, b0.y, b0.z, b0.w, b1.x, b1.y, b1.z, b1.w};
#pragma unroll
      for (int q = 0; q < 4; ++q)
#pragma unroll
        for (int j = 0; j < 8; ++j) {
          acc[q][j] = fmaf(x1[q], k1[j], acc[q][j]);
          acc[q][j] = fmaf(x2[q], k2[j], acc[q][j]);
        }
    }
    __syncthreads();
  }

  long e = e0 + 4 * ng;
#pragma unroll
  for (int j = 0; j < 8; ++j) {
    long o = 8 * og + j;
    float4 v = make_float4(acc[0][j], acc[1][j], acc[2][j], acc[3][j]);
    if (e + 3 < N) {
      *(float4*)&out[o * N + e] = v;
    } else {
      const float* pv = &v.x;
      for (int q = 0; q < 4; ++q)
        if (e + q < N) out[o * N + e + q] = pv[q];
    }
  }
}

// ---------------------------------------------------------------------------
// CSR build: counts -> scan -> fill. Entry = (e<<1)|sign (sign 1 => minus).
// ---------------------------------------------------------------------------
__global__ __launch_bounds__(256) void count_deg(const int* __restrict__ iInd,
                                                 const int* __restrict__ jInd,
                                                 const int nE,
                                                 int* __restrict__ cnt) {
  const int e = blockIdx.x * 256 + threadIdx.x;
  if (e >= nE) return;
  atomicAdd(&cnt[iInd[e]], 1);
  atomicAdd(&cnt[jInd[e]], 1);
}

__global__ __launch_bounds__(1024) void scan_rowptr(const int* __restrict__ cnt,
                                                    int* __restrict__ rp,
                                                    const int nN) {
  __shared__ int buf[1024];
  __shared__ int carry;
  const int tid = threadIdx.x;
  if (tid == 0) {
    carry = 0;
    rp[0] = 0;
  }
  __syncthreads();
  for (int base = 0; base < nN; base += 1024) {
    int idx = base + tid;
    int v = (idx < nN) ? cnt[idx] : 0;
    buf[tid] = v;
    __syncthreads();
    for (int off = 1; off < 1024; off <<= 1) {
      int t = (tid >= off) ? buf[tid - off] : 0;
      __syncthreads();
      buf[tid] += t;
      __syncthreads();
    }
    if (idx < nN) rp[idx + 1] = buf[tid] + carry;
    __syncthreads();
    if (tid == 0) carry += buf[1023];
    __syncthreads();
  }
}

__global__ __launch_bounds__(256) void fill_adj(const int* __restrict__ iInd,
                                                const int* __restrict__ jInd,
                                                const int nE,
                                                const int* __restrict__ rp,
                                                int* __restrict__ cur,
                                                int* __restrict__ adj) {
  const int e = blockIdx.x * 256 + threadIdx.x;
  if (e >= nE) return;
  const int ii = iInd[e], jj = jInd[e];
  int s1 = atomicAdd(&cur[ii], 1);
  adj[rp[ii] + s1] = (e << 1);
  int s2 = atomicAdd(&cur[jj], 1);
  adj[rp[jj] + s2] = (e << 1) | 1;
}

// ---------------------------------------------------------------------------
// div_gather: D[n,:] = (OPEN ? 0 : D0[n,:]) + sum_{(e,s) in adj(n)} +-E[e,:]
// 32 lanes per node (float4/lane over 128 ch), 8 nodes per block.
// ---------------------------------------------------------------------------
template <bool OPEN>
__global__ __launch_bounds__(256) void div_gather(
    const float* __restrict__ E, const int* __restrict__ rp,
    const int* __restrict__ adj, const float* __restrict__ D0,
    float* __restrict__ D, const int nN) {
  const int cg = threadIdx.x & 31, slot = threadIdx.x >> 5;
  const long n = (long)blockIdx.x * 8 + slot;
  if (n >= nN) return;
  const float4* E4 = (const float4*)E;
  float4 acc;
  if (OPEN) {
    acc = f4z();
  } else {
    acc = ((const float4*)D0)[n * 32 + cg];
  }
  const int b = rp[n], en = rp[n + 1];
  for (int k = b; k < en; ++k) {
    const int ent = adj[k];
    const long e = ent >> 1;
    const float4 v = E4[e * 32 + cg];
    if (ent & 1) {
      acc.x -= v.x; acc.y -= v.y; acc.z -= v.z; acc.w -= v.w;
    } else {
      acc.x += v.x; acc.y += v.y; acc.z += v.z; acc.w += v.w;
    }
  }
  ((float4*)D)[n * 32 + cg] = acc;
}

// ---------------------------------------------------------------------------
// Edge pass 1: per-channel sum/sumsq of y = W[i]-W[j].
// ---------------------------------------------------------------------------
__global__ __launch_bounds__(256) void edge_pass1(
    const float* __restrict__ W, const int* __restrict__ iInd,
    const int* __restrict__ jInd, const int nE, float* __restrict__ statS,
    float* __restrict__ statQ) {
  __shared__ float4 rs[256];
  __shared__ float4 rq[256];
  const int tid = threadIdx.x;
  const int cg = tid & 31, slot = tid >> 5;
  const float4* W4 = (const float4*)W;
  float4 s = f4z(), q = f4z();
  long start = (long)blockIdx.x * 512;
  long end = start + 512;
  if (end > nE) end = nE;
  for (long e = start + slot; e < end; e += 8) {
    const int ii = iInd[e], jj = jInd[e];
    const float4 wi = W4[(long)ii * 32 + cg];
    const float4 wj = W4[(long)jj * 32 + cg];
    const float y0 = wi.x - wj.x, y1 = wi.y - wj.y;
    const float y2 = wi.z - wj.z, y3 = wi.w - wj.w;
    s.x += y0; s.y += y1; s.z += y2; s.w += y3;
    q.x = fmaf(y0, y0, q.x); q.y = fmaf(y1, y1, q.y);
    q.z = fmaf(y2, y2, q.z); q.w = fmaf(y3, y3, q.w);
  }
  rs[tid] = s;
  rq[tid] = q;
  __syncthreads();
  if (tid < 32) {
    float4 S = rs[tid], Q = rq[tid];
#pragma unroll
    for (int g = 1; g < 8; ++g) {
      float4 a = rs[tid + 32 * g], b = rq[tid + 32 * g];
      S.x += a.x; S.y += a.y; S.z += a.z; S.w += a.w;
      Q.x += b.x; Q.y += b.y; Q.z += b.z; Q.w += b.w;
    }
    atomicAdd(&statS[tid * 4 + 0], S.x);
    atomicAdd(&statS[tid * 4 + 1], S.y);
    atomicAdd(&statS[tid * 4 + 2], S.z);
    atomicAdd(&statS[tid * 4 + 3], S.w);
    atomicAdd(&statQ[tid * 4 + 0], Q.x);
    atomicAdd(&statQ[tid * 4 + 1], Q.y);
    atomicAdd(&statQ[tid * 4 + 2], Q.z);
    atomicAdd(&statQ[tid * 4 + 3], Q.w);
  }
}

// ---------------------------------------------------------------------------
// Edge pass 2: r = H*relu((y-mean)*rsig); Sacc (=) or (+=) r. No atomics.
// ---------------------------------------------------------------------------
template <bool FIRST>
__global__ __launch_bounds__(256) void edge_pass2(
    const float* __restrict__ W, const int* __restrict__ iInd,
    const int* __restrict__ jInd, const int nE, const float* __restrict__ mean,
    const float* __restrict__ rsig, float* __restrict__ Sacc) {
  const int tid = threadIdx.x;
  const int cg = tid & 31, slot = tid >> 5;
  const float4 mu = *(const float4*)&mean[cg * 4];
  const float4 sg = *(const float4*)&rsig[cg * 4];
  const float4* W4 = (const float4*)W;
  float4* S4 = (float4*)Sacc;
  long start = (long)blockIdx.x * 512;
  long end = start + 512;
  if (end > nE) end = nE;
  for (long e = start + slot; e < end; e += 8) {
    const int ii = iInd[e], jj = jInd[e];
    const float4 wi = W4[(long)ii * 32 + cg];
    const float4 wj = W4[(long)jj * 32 + cg];
    const float r0 = fmaxf(((wi.x - wj.x) - mu.x) * sg.x, 0.f) * HSTEP;
    const float r1 = fmaxf(((wi.y - wj.y) - mu.y) * sg.y, 0.f) * HSTEP;
    const float r2 = fmaxf(((wi.z - wj.z) - mu.z) * sg.z, 0.f) * HSTEP;
    const float r3 = fmaxf(((wi.w - wj.w) - mu.w) * sg.w, 0.f) * HSTEP;
    float4 sv;
    if (FIRST) {
      sv = make_float4(r0, r1, r2, r3);
    } else {
      sv = S4[e * 32 + cg];
      sv.x += r0; sv.y += r1; sv.z += r2; sv.w += r3;
    }
    S4[e * 32 + cg] = sv;
  }
}

// ---------------------------------------------------------------------------
__global__ void fin_stats(const float* __restrict__ S,
                          const float* __restrict__ Q, const float cnt,
                          float* __restrict__ mean, float* __restrict__ rsig) {
  const int c = threadIdx.x;  // 128
  const float mu = S[c] / cnt;
  const float var = Q[c] - cnt * mu * mu;
  mean[c] = mu;
  rsig[c] = rsqrtf(var + TVEPS);
}

__global__ __launch_bounds__(256) void apply_node(
    const float* __restrict__ R, const float* __restrict__ mean,
    const float* __restrict__ rsig, float* __restrict__ xnt,
    const long total4) {
  const long idx = (long)blockIdx.x * 256 + threadIdx.x;
  if (idx >= total4) return;
  const int o4 = (int)(idx & 31) * 4;
  const float4 m = *(const float4*)&mean[o4];
  const float4 s = *(const float4*)&rsig[o4];
  const float4 r = ((const float4*)R)[idx];
  float4 x = ((float4*)xnt)[idx];
  x.x += HSTEP * fmaxf((r.x - m.x) * s.x, 0.f);
  x.y += HSTEP * fmaxf((r.y - m.y) * s.y, 0.f);
  x.z += HSTEP * fmaxf((r.z - m.z) * s.z, 0.f);
  x.w += HSTEP * fmaxf((r.w - m.w) * s.w, 0.f);
  ((float4*)xnt)[idx] = x;
}

__global__ void make_m1(const float* __restrict__ KNclose,
                        const float* __restrict__ KEopen,
                        float* __restrict__ M1) {
  const int idx = blockIdx.x * 256 + threadIdx.x;  // 16384
  const int o = idx >> 7, k = idx & 127;
  float s = 0.f;
  for (int m = 0; m < 128; ++m)
    s = fmaf(KNclose[o * 128 + m], KEopen[m * 128 + k], s);
  M1[idx] = s;
}

// ---------------------------------------------------------------------------
extern "C" void kernel_launch(void* const* d_in, const int* in_sizes, int n_in,
                              void* d_out, int out_size, void* d_ws,
                              size_t ws_size, hipStream_t stream) {
  const float* xn = (const float*)d_in[0];
  const float* xe = (const float*)d_in[1];
  const int* iInd = (const int*)d_in[2];
  const int* jInd = (const int*)d_in[3];
  const float* KNopen = (const float*)d_in[4];
  const float* KEopen = (const float*)d_in[5];
  const float* KNclose = (const float*)d_in[6];
  const float* KN = (const float*)d_in[8];
  const float* KE = (const float*)d_in[9];

  const int nN = in_sizes[0] / 128;
  const int nE = in_sizes[2];

  float* out_xn = (float*)d_out;
  float* out_xe = (float*)d_out + (size_t)128 * nN;

  float* ws = (float*)d_ws;
  size_t off = 0;
  float* Sacc = ws + off; off += (size_t)nE * 128;  // 256 MB; aliases Eopen
  float* W    = ws + off; off += (size_t)nN * 128;  // also reused as R
  float* Dacc = ws + off; off += (size_t)nN * 128;
  float* D0   = ws + off; off += (size_t)nN * 128;
  float* xnt  = ws + off; off += (size_t)nN * 128;
  float* M1   = ws + off; off += 16384;
  float* stats = ws + off; off += 1024;
  float* statS = stats;        float* statQ = stats + 128;
  float* meanE = stats + 256;  float* rsigE = stats + 384;
  float* statS2 = stats + 512; float* statQ2 = stats + 640;
  float* meanN = stats + 768;  float* rsigN = stats + 896;
  int* rp  = (int*)(ws + off); off += (size_t)nN + 1 + 63;  // row_ptr
  int* cnt = (int*)(ws + off); off += nN;
  int* cur = (int*)(ws + off); off += nN;
  int* adj = (int*)(ws + off); off += (size_t)2 * nE;
  float* Eopen = Sacc;  // alias: Eopen dead after div_gather<true>
  float* R = W;         // alias: W dead after edge_pass2

  const int gN = (nN + 63) / 64;
  const int gE = (nE + 63) / 64;
  const int gP = (nE + 511) / 512;
  const int gEdge = (nE + 255) / 256;
  const int gGath = (nN + 7) / 8;
  const int gA = (int)(((long)nN * 32 + 255) / 256);

  // ---- CSR build ----
  hipMemsetAsync(cnt, 0, (size_t)nN * sizeof(int), stream);
  hipMemsetAsync(cur, 0, (size_t)nN * sizeof(int), stream);
  count_deg<<<gEdge, 256, 0, stream>>>(iInd, jInd, nE, cnt);
  scan_rowptr<<<1, 1024, 0, stream>>>(cnt, rp, nN);
  fill_adj<<<gEdge, 256, 0, stream>>>(iInd, jInd, nE, rp, cur, adj);

  // ---- open ----
  gemm_e<<<gN, 256, 0, stream>>>(xn, KNopen, nN, xnt);          // xnt [nN,128]
  gemm_e<<<gE, 256, 0, stream>>>(xe, KEopen, nE, Eopen);        // [nE,128]
  make_m1<<<64, 256, 0, stream>>>(KNclose, KEopen, M1);
  div_gather<true><<<gGath, 256, 0, stream>>>(Eopen, rp, adj, nullptr, D0, nN);

  // ---- layers ----
  for (int layer = 0; layer < 4; ++layer) {
    hipMemsetAsync(stats, 0, 1024 * sizeof(float), stream);
    gemm_n<0><<<gN, 256, 0, stream>>>(xnt, KN + layer * 16384, nN, W, nullptr,
                                      nullptr);
    edge_pass1<<<gP, 256, 0, stream>>>(W, iInd, jInd, nE, statS, statQ);
    fin_stats<<<1, 128, 0, stream>>>(statS, statQ, (float)nE, meanE, rsigE);
    if (layer == 0)
      edge_pass2<true><<<gP, 256, 0, stream>>>(W, iInd, jInd, nE, meanE, rsigE,
                                               Sacc);
    else
      edge_pass2<false><<<gP, 256, 0, stream>>>(W, iInd, jInd, nE, meanE,
                                                rsigE, Sacc);
    div_gather<false><<<gGath, 256, 0, stream>>>(Sacc, rp, adj, D0, Dacc, nN);
    gemm_n<1><<<gN, 256, 0, stream>>>(Dacc, KE + layer * 16384, nN, R, statS2,
                                      statQ2);
    fin_stats<<<1, 128, 0, stream>>>(statS2, statQ2, (float)nN, meanN, rsigN);
    apply_node<<<gA, 256, 0, stream>>>(R, meanN, rsigN, xnt, (long)nN * 32);
  }

  // ---- close ----
  gemm_n<2><<<gN, 256, 0, stream>>>(xnt, KNclose, nN, out_xn, nullptr,
                                    nullptr);
  close_edge<<<gE, 256, 0, stream>>>(xe, Sacc, M1, KNclose, nE, out_xe);
}